// Round 1
// 970.191 us; speedup vs baseline: 1.1759x; 1.1759x over previous
//
#include <hip/hip_runtime.h>
#include <stdint.h>

// RWKV-4 block: B=8, T=2048, C=1024, DIM_FFN=4096, fp32 in/out, bf16 MFMA internally.
#define B_ 8
#define T_ 2048
#define C_ 1024
#define F_ 4096
#define M_ (B_*T_)   // 16384 rows
#define NC 16        // WKV chunks per sequence
#define LCH (T_/NC)  // 128 steps per chunk

typedef __attribute__((ext_vector_type(8))) short bf16x8;   // MFMA A/B frag (4 VGPRs)
typedef __attribute__((ext_vector_type(4))) float f32x4;    // MFMA C/D frag

static __device__ __forceinline__ unsigned short f2bf(float f) {
    union { float f; unsigned u; } v; v.f = f;
    unsigned r = v.u + 0x7fffu + ((v.u >> 16) & 1u);  // RNE
    return (unsigned short)(r >> 16);
}
static __device__ __forceinline__ float bf2f(unsigned short h) {
    union { unsigned u; float f; } v; v.u = ((unsigned)h) << 16;
    return v.f;
}

// async global->LDS, 16B/lane, wave-uniform LDS base + lane*16 (m97 pattern)
#define GLDS16(gp, lp) __builtin_amdgcn_global_load_lds( \
    (const __attribute__((address_space(1))) unsigned int*)(gp), \
    (__attribute__((address_space(3))) unsigned int*)(lp), 16, 0, 0)

#define SB0() __builtin_amdgcn_sched_barrier(0)

// ---------------------------------------------------------------------------
// Weight conversion fp32 -> bf16 into one packed ws region (13M elems, 26MB).
// dst element layout: [Wk 1M][Wv 1M][Wr 1M][Wo 1M][Wrec 1M][Wkey 4M][Wval 4M]
// ---------------------------------------------------------------------------
struct WSrc { const float* p[7]; };

__global__ __launch_bounds__(256) void k_convert(WSrc w, unsigned short* __restrict__ dst) {
    size_t e = ((size_t)blockIdx.x * 256 + threadIdx.x) * 4;
    int seg = (int)(e >> 20);
    const float* s; size_t off;
    if (seg < 5)      { s = w.p[seg]; off = e - ((size_t)seg << 20); }
    else if (seg < 9) { s = w.p[5];   off = e - (5ull << 20); }
    else              { s = w.p[6];   off = e - (9ull << 20); }
    float4 v = *(const float4*)(s + off);
    ushort4 o;
    o.x = f2bf(v.x); o.y = f2bf(v.y); o.z = f2bf(v.z); o.w = f2bf(v.w);
    *(ushort4*)(dst + e) = o;
}

// ---------------------------------------------------------------------------
// Fused LayerNorm + time_shift + token-mix. One block per row m = b*T+t.
// ---------------------------------------------------------------------------
template<int THREE>
__global__ __launch_bounds__(256) void k_ln_mix(
    const float* __restrict__ xin, const float* __restrict__ lw, const float* __restrict__ lb,
    const float* __restrict__ tk, const float* __restrict__ tv, const float* __restrict__ tr,
    unsigned short* __restrict__ ok, unsigned short* __restrict__ ov, unsigned short* __restrict__ orr)
{
    __shared__ float sred[4][4];
    const int m = blockIdx.x;
    const int t = m & (T_ - 1);
    const int tid = threadIdx.x;
    const int col0 = tid * 4;

    const float4 xc = *(const float4*)(xin + (size_t)m * C_ + col0);
    float4 xp = make_float4(0.f, 0.f, 0.f, 0.f);
    if (t > 0) xp = *(const float4*)(xin + (size_t)(m - 1) * C_ + col0);

    float s1 = xc.x + xc.y + xc.z + xc.w;
    float s2 = xc.x*xc.x + xc.y*xc.y + xc.z*xc.z + xc.w*xc.w;
    float s3 = xp.x + xp.y + xp.z + xp.w;
    float s4 = xp.x*xp.x + xp.y*xp.y + xp.z*xp.z + xp.w*xp.w;
    #pragma unroll
    for (int off = 32; off > 0; off >>= 1) {
        s1 += __shfl_down(s1, off);
        s2 += __shfl_down(s2, off);
        s3 += __shfl_down(s3, off);
        s4 += __shfl_down(s4, off);
    }
    const int wave = tid >> 6, lane = tid & 63;
    if (lane == 0) { sred[0][wave]=s1; sred[1][wave]=s2; sred[2][wave]=s3; sred[3][wave]=s4; }
    __syncthreads();
    const float S1 = sred[0][0]+sred[0][1]+sred[0][2]+sred[0][3];
    const float S2 = sred[1][0]+sred[1][1]+sred[1][2]+sred[1][3];
    const float S3 = sred[2][0]+sred[2][1]+sred[2][2]+sred[2][3];
    const float S4 = sred[3][0]+sred[3][1]+sred[3][2]+sred[3][3];

    const float inv = 1.0f / (float)C_;
    const float muc = S1 * inv;
    const float rc  = rsqrtf(S2 * inv - muc * muc + 1e-5f);
    const float mup = S3 * inv;
    const float rp  = rsqrtf(S4 * inv - mup * mup + 1e-5f);

    const float xcv[4] = {xc.x, xc.y, xc.z, xc.w};
    const float xpv[4] = {xp.x, xp.y, xp.z, xp.w};
    unsigned short rk[4], rv[4], rr[4];
    #pragma unroll
    for (int i = 0; i < 4; ++i) {
        const int col = col0 + i;
        const float w_ = lw[col], b_ = lb[col];
        const float h  = (xcv[i] - muc) * rc * w_ + b_;
        const float hh = (t > 0) ? (xpv[i] - mup) * rp * w_ + b_ : 0.f;
        const float ak = tk[col];
        rk[i] = f2bf(h * ak + hh * (1.f - ak));
        if (THREE) { const float av = tv[col]; rv[i] = f2bf(h * av + hh * (1.f - av)); }
        const float ar = tr[col];
        rr[i] = f2bf(h * ar + hh * (1.f - ar));
    }
    const size_t o = (size_t)m * C_ + col0;
    ushort4 u;
    u.x = rk[0]; u.y = rk[1]; u.z = rk[2]; u.w = rk[3];
    *(ushort4*)(ok + o) = u;
    if (THREE) {
        u.x = rv[0]; u.y = rv[1]; u.z = rv[2]; u.w = rv[3];
        *(ushort4*)(ov + o) = u;
    }
    u.x = rr[0]; u.y = rr[1]; u.z = rr[2]; u.w = rr[3];
    *(ushort4*)(orr + o) = u;
}

// ---------------------------------------------------------------------------
// WKV pass A: per (b,c,chunk) local state recurrence from zero init.
// ---------------------------------------------------------------------------
__global__ __launch_bounds__(256) void k_wkv_local(
    const unsigned short* __restrict__ kb, const unsigned short* __restrict__ vb,
    const float* __restrict__ tdec, float4* __restrict__ st)
{
    const int g = blockIdx.x * 256 + threadIdx.x;   // 0..131071
    const int c = g & (C_ - 1);
    const int j = (g >> 10) & (NC - 1);
    const int b = g >> 14;
    const float w = -__expf(tdec[c]);
    float aa = 0.f, bb = 0.f, pp = -1e38f;
    const size_t base = ((size_t)(b * T_ + j * LCH)) * C_ + c;
    #pragma unroll 4
    for (int t = 0; t < LCH; ++t) {
        const float kt = bf2f(kb[base + (size_t)t * C_]);
        const float vt = bf2f(vb[base + (size_t)t * C_]);
        const float ww2 = pp + w;
        const float qq2 = fmaxf(ww2, kt);
        const float e1b = __expf(ww2 - qq2);
        const float e2b = __expf(kt - qq2);
        aa = e1b * aa + e2b * vt;
        bb = e1b * bb + e2b;
        pp = qq2;
    }
    st[((size_t)b * NC + j) * C_ + c] = make_float4(aa, bb, pp, 0.f);
}

// ---------------------------------------------------------------------------
// WKV pass C: combine preceding chunk states, replay chunk computing p=sr*y.
// ---------------------------------------------------------------------------
__global__ __launch_bounds__(256) void k_wkv_scan(
    const unsigned short* __restrict__ kb, const unsigned short* __restrict__ vb,
    const unsigned short* __restrict__ sr,
    const float* __restrict__ tdec, const float* __restrict__ tfirst,
    const float4* __restrict__ st, unsigned short* __restrict__ p)
{
    const int g = blockIdx.x * 256 + threadIdx.x;
    const int c = g & (C_ - 1);
    const int j = (g >> 10) & (NC - 1);
    const int b = g >> 14;
    const float w = -__expf(tdec[c]);
    const float u = tfirst[c];

    float aa = 0.f, bb = 0.f, pp = -1e38f;
    for (int i = 0; i < j; ++i) {
        const float4 s = st[((size_t)b * NC + i) * C_ + c];
        const float pdec = pp + w * (float)LCH;
        const float q  = fmaxf(pdec, s.z);
        const float eA = __expf(pdec - q);
        const float eB = __expf(s.z - q);
        aa = eA * aa + eB * s.x;
        bb = eA * bb + eB * s.y;
        pp = q;
    }

    const size_t base = ((size_t)(b * T_ + j * LCH)) * C_ + c;
    #pragma unroll 4
    for (int t = 0; t < LCH; ++t) {
        const size_t idx = base + (size_t)t * C_;
        const float kt = bf2f(kb[idx]);
        const float vt = bf2f(vb[idx]);
        const float ww = u + kt;
        const float qq = fmaxf(pp, ww);
        const float e1 = __expf(pp - qq);
        const float e2 = __expf(ww - qq);
        const float y  = (e1 * aa + e2 * vt) / (e1 * bb + e2);
        p[idx] = f2bf(bf2f(sr[idx]) * y);
        const float ww2 = pp + w;
        const float qq2 = fmaxf(ww2, kt);
        const float e1b = __expf(ww2 - qq2);
        const float e2b = __expf(kt - qq2);
        aa = e1b * aa + e2b * vt;
        bb = e1b * bb + e2b;
        pp = qq2;
    }
}

// ---------------------------------------------------------------------------
// 8-phase GEMM core (T2+T3+T4+T5): BM=BN=256, BK=32, 8 waves (2M x 4N),
// per-wave C = 128x64 (acc[8][4] 16x16 frags). LDS = 3-slot ring per matrix
// (slot = 256x32 bf16 = 16 KiB; A 48 KiB + B 48 KiB = 96 KiB).
//
// Ring schedule (provably race-free counted vmcnt):
//   while computing K-tile t from slot t%3, stage tile t+2 into slot (t+2)%3
//   (slot (t+1)%3 holds tile t+1, untouched). End-of-tile wait is
//   s_waitcnt vmcnt(4): allows tile t+2's 4 loads to stay in flight, proves
//   tile t+1 (issued during tile t-1) complete. Never drains to 0 (T4).
//
// Per K-tile: 2 phases x {ds_read subtile || 2x global_load_lds -> barrier ->
// lgkmcnt(0) -> setprio(1) -> 16 MFMA -> setprio(0) -> barrier}.
//
// Swizzle (T2, both-sides-or-neither, rule #21): row r (64 B = 4 x 16B blocks):
// logical block q stored at physical q ^ swz(r), swz(r)=(r&3)^((r>>2)&3).
// Applied by pre-swizzling the global SOURCE address (LDS dest stays linear
// for global_load_lds) and XOR-ing the read address. Evenness check: per
// 16-lane quad-group each (row-parity, block) bank class gets exactly 2 lanes
// -> conflict-free b128.
// ---------------------------------------------------------------------------
static __device__ __forceinline__ void gemm_core8(
    const unsigned short* __restrict__ A, int lda,
    const unsigned short* __restrict__ Bw, int ldb,
    int K, int m0, int n0,
    unsigned short* As, unsigned short* Bs, f32x4 acc[8][4])
{
    const int tid  = threadIdx.x;
    const int w    = tid >> 6, l = tid & 63;
    const int l16  = l & 15, quad = l >> 4;
    const int wm   = w >> 2, wn = w & 3;        // 2 x 4 wave grid

    // ---- staging source addressing (pre-swizzled global, linear LDS dest)
    // round R covers rows R*128..R*128+127; wave w rows w*16+(l>>2); block l&3
    const int swz_s = ((l >> 2) & 3) ^ ((l >> 4) & 3);   // = swz(dest row)
    const int blk_s = (l & 3) ^ swz_s;                   // logical block to fetch
    const unsigned short* gA0 = A  + (size_t)(m0 + w * 16 + (l >> 2)) * lda + blk_s * 8;
    const unsigned short* gA1 = gA0 + (size_t)128 * lda;
    const unsigned short* gB0 = Bw + (size_t)(n0 + w * 16 + (l >> 2)) * ldb + blk_s * 8;
    const unsigned short* gB1 = gB0 + (size_t)128 * ldb;

    auto stageA = [&](int tt, int ss) {
        const size_t ko = (size_t)tt * 32;
        GLDS16(gA0 + ko, As + ss * 8192 + w * 512);
        GLDS16(gA1 + ko, As + ss * 8192 + 4096 + w * 512);
    };
    auto stageB = [&](int tt, int ss) {
        const size_t ko = (size_t)tt * 32;
        GLDS16(gB0 + ko, Bs + ss * 8192 + w * 512);
        GLDS16(gB1 + ko, Bs + ss * 8192 + 4096 + w * 512);
    };

    // ---- fragment read addressing (swizzled): row = band + frag*16 + l16,
    // physical block = quad ^ swz(row); swz(row) depends only on l16.
    const int pswz = (l16 & 3) ^ ((l16 >> 2) & 3);
    const unsigned short* aRd = As + (wm * 128 + l16) * 32 + ((quad ^ pswz) << 3);
    const unsigned short* bRd = Bs + (wn * 64  + l16) * 32 + ((quad ^ pswz) << 3);

    // ---- prologue: stage tiles 0 and 1; wait tile 0 (4 newest stay in flight)
    stageA(0, 0); stageB(0, 0);
    stageA(1, 1); stageB(1, 1);
    asm volatile("s_waitcnt vmcnt(4)" ::: "memory");
    SB0();
    __builtin_amdgcn_s_barrier();
    SB0();

    const int NT = K >> 5;
    int rs = 0, ws2 = 2;
    for (int t = 0; t < NT; ++t) {
        const unsigned short* ab = aRd + rs * 8192;
        const unsigned short* bb = bRd + rs * 8192;
        bf16x8 af[4], bf[4];

        // ===== phase 0: B frags + A frags 0..3, stage A(t+2), 16 MFMA =====
        #pragma unroll
        for (int j = 0; j < 4; ++j) bf[j] = *(const bf16x8*)(bb + j * 512);
        #pragma unroll
        for (int i = 0; i < 4; ++i) af[i] = *(const bf16x8*)(ab + i * 512);
        if (t + 2 < NT) stageA(t + 2, ws2);
        SB0();
        __builtin_amdgcn_s_barrier();
        asm volatile("s_waitcnt lgkmcnt(0)" ::: "memory");
        SB0();
        __builtin_amdgcn_s_setprio(1);
        #pragma unroll
        for (int i = 0; i < 4; ++i)
            #pragma unroll
            for (int j = 0; j < 4; ++j)
                acc[i][j] = __builtin_amdgcn_mfma_f32_16x16x32_bf16(af[i], bf[j], acc[i][j], 0, 0, 0);
        __builtin_amdgcn_s_setprio(0);
        SB0();
        __builtin_amdgcn_s_barrier();
        SB0();

        // ===== phase 1: A frags 4..7 (B reused), stage B(t+2), 16 MFMA =====
        bf16x8 ag[4];
        #pragma unroll
        for (int i = 0; i < 4; ++i) ag[i] = *(const bf16x8*)(ab + (4 + i) * 512);
        if (t + 2 < NT) stageB(t + 2, ws2);
        SB0();
        __builtin_amdgcn_s_barrier();
        asm volatile("s_waitcnt lgkmcnt(0)" ::: "memory");
        SB0();
        __builtin_amdgcn_s_setprio(1);
        #pragma unroll
        for (int i = 0; i < 4; ++i)
            #pragma unroll
            for (int j = 0; j < 4; ++j)
                acc[4 + i][j] = __builtin_amdgcn_mfma_f32_16x16x32_bf16(ag[i], bf[j], acc[4 + i][j], 0, 0, 0);
        __builtin_amdgcn_s_setprio(0);
        // counted boundary wait: tile t+1 complete, tile t+2 may stay in flight
        asm volatile("s_waitcnt vmcnt(4)" ::: "memory");
        SB0();
        __builtin_amdgcn_s_barrier();
        SB0();

        rs  = (rs  == 2) ? 0 : rs + 1;
        ws2 = (ws2 == 2) ? 0 : ws2 + 1;
    }
}

// Generic GEMM. EPI: 1 = sigmoid->bf16; 2 = resid + acc -> fp32;
//                3 = relu(acc)^2 -> bf16; 4 = outF += bf16(mul)*acc
template<int EPI>
__global__ __launch_bounds__(512, 2) void k_gemm(
    const unsigned short* __restrict__ A, int lda,
    const unsigned short* __restrict__ Bw, int ldb,
    int K, int N,
    float* __restrict__ outF, unsigned short* __restrict__ outH,
    const float* __restrict__ resid, const unsigned short* __restrict__ mul)
{
    __shared__ unsigned short As[3 * 8192];   // 48 KiB
    __shared__ unsigned short Bs[3 * 8192];   // 48 KiB
    f32x4 acc[8][4];
    const f32x4 zero = {0.f, 0.f, 0.f, 0.f};
    #pragma unroll
    for (int i = 0; i < 8; ++i)
        #pragma unroll
        for (int j = 0; j < 4; ++j) acc[i][j] = zero;

    const int m0 = blockIdx.x * 256, n0 = blockIdx.y * 256;
    gemm_core8(A, lda, Bw, ldb, K, m0, n0, As, Bs, acc);

    const int lane = threadIdx.x & 63, wave = threadIdx.x >> 6;
    const int quad = lane >> 4, l16 = lane & 15;
    const int wm = (wave >> 2) * 128, wn = (wave & 3) * 64;
    #pragma unroll
    for (int i = 0; i < 8; ++i) {
        const int rowb = m0 + wm + i * 16 + quad * 4;
        #pragma unroll
        for (int j = 0; j < 4; ++j) {
            const int col = n0 + wn + j * 16 + l16;
            #pragma unroll
            for (int r = 0; r < 4; ++r) {
                const size_t idx = (size_t)(rowb + r) * N + col;
                const float v = acc[i][j][r];
                if (EPI == 1)      outH[idx] = f2bf(1.f / (1.f + __expf(-v)));
                else if (EPI == 2) outF[idx] = resid[idx] + v;
                else if (EPI == 3) { const float z = v > 0.f ? v : 0.f; outH[idx] = f2bf(z * z); }
                else               outF[idx] = outF[idx] + bf2f(mul[idx]) * v;
            }
        }
    }
}

// Fused k/v/r projection: one dispatch vs packed [Wk;Wv;Wr] (N=3072).
// n-segment (n0>>10, uniform per block) selects BOTH the A input (xk/xv/xr)
// and the output (k->ok, v->ov, sigmoid(r)->orr). 256-tiles divide 1024.
__global__ __launch_bounds__(512, 2) void k_gemm_kvr(
    const unsigned short* __restrict__ xk, const unsigned short* __restrict__ xv,
    const unsigned short* __restrict__ xr,
    const unsigned short* __restrict__ W3,
    unsigned short* __restrict__ ok, unsigned short* __restrict__ ov,
    unsigned short* __restrict__ orr)
{
    __shared__ unsigned short As[3 * 8192];
    __shared__ unsigned short Bs[3 * 8192];
    f32x4 acc[8][4];
    const f32x4 zero = {0.f, 0.f, 0.f, 0.f};
    #pragma unroll
    for (int i = 0; i < 8; ++i)
        #pragma unroll
        for (int j = 0; j < 4; ++j) acc[i][j] = zero;

    const int m0 = blockIdx.x * 256, n0 = blockIdx.y * 256;
    const int seg = n0 >> 10;                       // 0=k 1=v 2=r
    const unsigned short* A = (seg == 0) ? xk : (seg == 1) ? xv : xr;
    unsigned short* outH    = (seg == 0) ? ok : (seg == 1) ? ov : orr;

    gemm_core8(A, C_, W3, C_, C_, m0, n0, As, Bs, acc);

    const int nl0 = n0 & (C_ - 1);
    const int lane = threadIdx.x & 63, wave = threadIdx.x >> 6;
    const int quad = lane >> 4, l16 = lane & 15;
    const int wm = (wave >> 2) * 128, wn = (wave & 3) * 64;
    #pragma unroll
    for (int i = 0; i < 8; ++i) {
        const int rowb = m0 + wm + i * 16 + quad * 4;
        #pragma unroll
        for (int j = 0; j < 4; ++j) {
            const int col = nl0 + wn + j * 16 + l16;
            #pragma unroll
            for (int r = 0; r < 4; ++r) {
                const size_t idx = (size_t)(rowb + r) * C_ + col;
                float v = acc[i][j][r];
                if (seg == 2) v = 1.f / (1.f + __expf(-v));
                outH[idx] = f2bf(v);
            }
        }
    }
}

// ---------------------------------------------------------------------------
// Workspace layout (peak 154 MB):
//   [0,32)MB    xk   -> WKV states (2MB) -> xk2
//   [32,64)     xv   -> p    -> tmp (FFN chunk)
//   [64,96)     xr   -> xr2
//   [96,128)    sr   -> s2
//   [128,154)   bf16 weights ([Wk;Wv;Wr] contiguous for fused GEMM)
// k,v (bf16, 32MB each) live in d_out until step 5 overwrites it.
// ---------------------------------------------------------------------------
extern "C" void kernel_launch(void* const* d_in, const int* in_sizes, int n_in,
                              void* d_out, int out_size, void* d_ws, size_t ws_size,
                              hipStream_t stream)
{
    const float* x      = (const float*)d_in[0];
    const float* ln1w   = (const float*)d_in[1];
    const float* ln1b   = (const float*)d_in[2];
    const float* ln2w   = (const float*)d_in[3];
    const float* ln2b   = (const float*)d_in[4];
    const float* atk    = (const float*)d_in[5];
    const float* atv    = (const float*)d_in[6];
    const float* atr    = (const float*)d_in[7];
    const float* tdec   = (const float*)d_in[8];
    const float* tfirst = (const float*)d_in[9];
    const float* Wk     = (const float*)d_in[10];
    const float* Wv     = (const float*)d_in[11];
    const float* Wr     = (const float*)d_in[12];
    const float* Wo     = (const float*)d_in[13];
    const float* ftk    = (const float*)d_in[14];
    const float* ftr    = (const float*)d_in[15];
    const float* Wkey   = (const float*)d_in[16];
    const float* Wrec   = (const float*)d_in[17];
    const float* Wval   = (const float*)d_in[18];
    float* out = (float*)d_out;

    char* ws = (char*)d_ws;
    const size_t MB = 1ull << 20;
    unsigned short* xk  = (unsigned short*)(ws + 0 * MB);
    unsigned short* xv  = (unsigned short*)(ws + 32 * MB);
    unsigned short* xr  = (unsigned short*)(ws + 64 * MB);
    unsigned short* sr  = (unsigned short*)(ws + 96 * MB);
    unsigned short* wb  = (unsigned short*)(ws + 128 * MB);
    float4* states      = (float4*)(ws + 0 * MB);   // 2MB, xk dead after kvr GEMM
    unsigned short* p   = xv;   // p overwrites xv (dead after kvr GEMM)
    unsigned short* xk2 = xk;
    unsigned short* xr2 = xr;
    unsigned short* s2  = sr;
    unsigned short* tmp = xv;   // FFN chunk buffer (p dead after Wo-GEMM)
    unsigned short* kb  = (unsigned short*)d_out;             // 32MB
    unsigned short* vb  = (unsigned short*)d_out + (32*MB/2); // 32MB

    unsigned short* W3_b   = wb;                   // [Wk;Wv;Wr] 3072x1024
    unsigned short* Wo_b   = wb + 3 * (1u << 20);
    unsigned short* Wrec_b = wb + 4 * (1u << 20);
    unsigned short* Wkey_b = wb + 5 * (1u << 20);
    unsigned short* Wval_b = wb + 9 * (1u << 20);

    // 1) weights -> bf16
    WSrc wsrc; wsrc.p[0]=Wk; wsrc.p[1]=Wv; wsrc.p[2]=Wr; wsrc.p[3]=Wo;
    wsrc.p[4]=Wrec; wsrc.p[5]=Wkey; wsrc.p[6]=Wval;
    k_convert<<<dim3(13312), dim3(256), 0, stream>>>(wsrc, wb);

    // 2) LN1 + time-shift mix -> xk, xv, xr (bf16)
    k_ln_mix<1><<<dim3(M_), dim3(256), 0, stream>>>(x, ln1w, ln1b, atk, atv, atr, xk, xv, xr);

    // 3) fused k/v/r projections (N=3072): k->kb, v->vb, sigmoid(r)->sr
    k_gemm_kvr<<<dim3(64, 12), dim3(512), 0, stream>>>(xk, xv, xr, W3_b, kb, vb, sr);

    // 4) WKV: chunk-parallel scan
    k_wkv_local<<<dim3(512), dim3(256), 0, stream>>>(kb, vb, tdec, states);
    k_wkv_scan<<<dim3(512), dim3(256), 0, stream>>>(kb, vb, sr, tdec, tfirst, states, p);

    // 5) x1 = x + p @ Wo^T -> d_out (fp32)
    k_gemm<2><<<dim3(64, 4), dim3(512), 0, stream>>>(p, 1024, Wo_b, 1024, 1024, 1024, out, (unsigned short*)nullptr, x, (const unsigned short*)nullptr);

    // 6) LN2 + time-shift mix -> xk2, xr2 (bf16)
    k_ln_mix<0><<<dim3(M_), dim3(256), 0, stream>>>(out, ln2w, ln2b, ftk, (const float*)nullptr, ftr, xk2, (unsigned short*)nullptr, xr2);

    // 7) s2 = sigmoid(xr2 @ Wrec^T) (bf16)
    k_gemm<1><<<dim3(64, 4), dim3(512), 0, stream>>>(xr2, 1024, Wrec_b, 1024, 1024, 1024, (float*)nullptr, s2, (const float*)nullptr, (const unsigned short*)nullptr);

    // 8) FFN chunked over F (4 x 1024): out += s2 * (relu(xk2@Wkey_f^T)^2 @ Wval_f^T)
    for (int f = 0; f < 4; ++f) {
        const unsigned short* WkeyF = Wkey_b + (size_t)f * 1024 * 1024;
        const unsigned short* WvalF = Wval_b + (size_t)f * 1024;
        k_gemm<3><<<dim3(64, 4), dim3(512), 0, stream>>>(xk2, 1024, WkeyF, 1024, 1024, 1024, (float*)nullptr, tmp, (const float*)nullptr, (const unsigned short*)nullptr);
        k_gemm<4><<<dim3(64, 4), dim3(512), 0, stream>>>(tmp, 1024, WvalF, 4096, 1024, 1024, out, (unsigned short*)nullptr, (const float*)nullptr, s2);
    }
}

// Round 2
// 943.259 us; speedup vs baseline: 1.2095x; 1.0286x over previous
//
#include <hip/hip_runtime.h>
#include <stdint.h>

// RWKV-4 block: B=8, T=2048, C=1024, DIM_FFN=4096, fp32 in/out, bf16 MFMA internally.
#define B_ 8
#define T_ 2048
#define C_ 1024
#define F_ 4096
#define M_ (B_*T_)   // 16384 rows
#define NC 16        // WKV chunks per sequence
#define LCH (T_/NC)  // 128 steps per chunk

typedef __attribute__((ext_vector_type(8))) short bf16x8;   // MFMA A/B frag (4 VGPRs)
typedef __attribute__((ext_vector_type(4))) float f32x4;    // MFMA C/D frag

static __device__ __forceinline__ unsigned short f2bf(float f) {
    union { float f; unsigned u; } v; v.f = f;
    unsigned r = v.u + 0x7fffu + ((v.u >> 16) & 1u);  // RNE
    return (unsigned short)(r >> 16);
}
static __device__ __forceinline__ float bf2f(unsigned short h) {
    union { unsigned u; float f; } v; v.u = ((unsigned)h) << 16;
    return v.f;
}

// async global->LDS, 16B/lane, wave-uniform LDS base + lane*16 (m97 pattern)
#define GLDS16(gp, lp) __builtin_amdgcn_global_load_lds( \
    (const __attribute__((address_space(1))) unsigned int*)(gp), \
    (__attribute__((address_space(3))) unsigned int*)(lp), 16, 0, 0)

#define SB0() __builtin_amdgcn_sched_barrier(0)
#define MFMA_BF16(a, b, c) __builtin_amdgcn_mfma_f32_16x16x32_bf16((a), (b), (c), 0, 0, 0)

// ---------------------------------------------------------------------------
// Weight conversion fp32 -> bf16 into one packed ws region (13M elems, 26MB).
// dst element layout: [Wk 1M][Wv 1M][Wr 1M][Wo 1M][Wrec 1M][Wkey 4M][Wval 4M]
// ---------------------------------------------------------------------------
struct WSrc { const float* p[7]; };

__global__ __launch_bounds__(256) void k_convert(WSrc w, unsigned short* __restrict__ dst) {
    size_t e = ((size_t)blockIdx.x * 256 + threadIdx.x) * 4;
    int seg = (int)(e >> 20);
    const float* s; size_t off;
    if (seg < 5)      { s = w.p[seg]; off = e - ((size_t)seg << 20); }
    else if (seg < 9) { s = w.p[5];   off = e - (5ull << 20); }
    else              { s = w.p[6];   off = e - (9ull << 20); }
    float4 v = *(const float4*)(s + off);
    ushort4 o;
    o.x = f2bf(v.x); o.y = f2bf(v.y); o.z = f2bf(v.z); o.w = f2bf(v.w);
    *(ushort4*)(dst + e) = o;
}

// ---------------------------------------------------------------------------
// Fused LayerNorm + time_shift + token-mix. One block per row m = b*T+t.
// ---------------------------------------------------------------------------
template<int THREE>
__global__ __launch_bounds__(256) void k_ln_mix(
    const float* __restrict__ xin, const float* __restrict__ lw, const float* __restrict__ lb,
    const float* __restrict__ tk, const float* __restrict__ tv, const float* __restrict__ tr,
    unsigned short* __restrict__ ok, unsigned short* __restrict__ ov, unsigned short* __restrict__ orr)
{
    __shared__ float sred[4][4];
    const int m = blockIdx.x;
    const int t = m & (T_ - 1);
    const int tid = threadIdx.x;
    const int col0 = tid * 4;

    const float4 xc = *(const float4*)(xin + (size_t)m * C_ + col0);
    float4 xp = make_float4(0.f, 0.f, 0.f, 0.f);
    if (t > 0) xp = *(const float4*)(xin + (size_t)(m - 1) * C_ + col0);

    float s1 = xc.x + xc.y + xc.z + xc.w;
    float s2 = xc.x*xc.x + xc.y*xc.y + xc.z*xc.z + xc.w*xc.w;
    float s3 = xp.x + xp.y + xp.z + xp.w;
    float s4 = xp.x*xp.x + xp.y*xp.y + xp.z*xp.z + xp.w*xp.w;
    #pragma unroll
    for (int off = 32; off > 0; off >>= 1) {
        s1 += __shfl_down(s1, off);
        s2 += __shfl_down(s2, off);
        s3 += __shfl_down(s3, off);
        s4 += __shfl_down(s4, off);
    }
    const int wave = tid >> 6, lane = tid & 63;
    if (lane == 0) { sred[0][wave]=s1; sred[1][wave]=s2; sred[2][wave]=s3; sred[3][wave]=s4; }
    __syncthreads();
    const float S1 = sred[0][0]+sred[0][1]+sred[0][2]+sred[0][3];
    const float S2 = sred[1][0]+sred[1][1]+sred[1][2]+sred[1][3];
    const float S3 = sred[2][0]+sred[2][1]+sred[2][2]+sred[2][3];
    const float S4 = sred[3][0]+sred[3][1]+sred[3][2]+sred[3][3];

    const float inv = 1.0f / (float)C_;
    const float muc = S1 * inv;
    const float rc  = rsqrtf(S2 * inv - muc * muc + 1e-5f);
    const float mup = S3 * inv;
    const float rp  = rsqrtf(S4 * inv - mup * mup + 1e-5f);

    const float xcv[4] = {xc.x, xc.y, xc.z, xc.w};
    const float xpv[4] = {xp.x, xp.y, xp.z, xp.w};
    unsigned short rk[4], rv[4], rr[4];
    #pragma unroll
    for (int i = 0; i < 4; ++i) {
        const int col = col0 + i;
        const float w_ = lw[col], b_ = lb[col];
        const float h  = (xcv[i] - muc) * rc * w_ + b_;
        const float hh = (t > 0) ? (xpv[i] - mup) * rp * w_ + b_ : 0.f;
        const float ak = tk[col];
        rk[i] = f2bf(h * ak + hh * (1.f - ak));
        if (THREE) { const float av = tv[col]; rv[i] = f2bf(h * av + hh * (1.f - av)); }
        const float ar = tr[col];
        rr[i] = f2bf(h * ar + hh * (1.f - ar));
    }
    const size_t o = (size_t)m * C_ + col0;
    ushort4 u;
    u.x = rk[0]; u.y = rk[1]; u.z = rk[2]; u.w = rk[3];
    *(ushort4*)(ok + o) = u;
    if (THREE) {
        u.x = rv[0]; u.y = rv[1]; u.z = rv[2]; u.w = rv[3];
        *(ushort4*)(ov + o) = u;
    }
    u.x = rr[0]; u.y = rr[1]; u.z = rr[2]; u.w = rr[3];
    *(ushort4*)(orr + o) = u;
}

// ---------------------------------------------------------------------------
// WKV pass A: per (b,c,chunk) local state recurrence from zero init.
// ---------------------------------------------------------------------------
__global__ __launch_bounds__(256) void k_wkv_local(
    const unsigned short* __restrict__ kb, const unsigned short* __restrict__ vb,
    const float* __restrict__ tdec, float4* __restrict__ st)
{
    const int g = blockIdx.x * 256 + threadIdx.x;   // 0..131071
    const int c = g & (C_ - 1);
    const int j = (g >> 10) & (NC - 1);
    const int b = g >> 14;
    const float w = -__expf(tdec[c]);
    float aa = 0.f, bb = 0.f, pp = -1e38f;
    const size_t base = ((size_t)(b * T_ + j * LCH)) * C_ + c;
    #pragma unroll 4
    for (int t = 0; t < LCH; ++t) {
        const float kt = bf2f(kb[base + (size_t)t * C_]);
        const float vt = bf2f(vb[base + (size_t)t * C_]);
        const float ww2 = pp + w;
        const float qq2 = fmaxf(ww2, kt);
        const float e1b = __expf(ww2 - qq2);
        const float e2b = __expf(kt - qq2);
        aa = e1b * aa + e2b * vt;
        bb = e1b * bb + e2b;
        pp = qq2;
    }
    st[((size_t)b * NC + j) * C_ + c] = make_float4(aa, bb, pp, 0.f);
}

// ---------------------------------------------------------------------------
// WKV pass C: combine preceding chunk states, replay chunk computing p=sr*y.
// ---------------------------------------------------------------------------
__global__ __launch_bounds__(256) void k_wkv_scan(
    const unsigned short* __restrict__ kb, const unsigned short* __restrict__ vb,
    const unsigned short* __restrict__ sr,
    const float* __restrict__ tdec, const float* __restrict__ tfirst,
    const float4* __restrict__ st, unsigned short* __restrict__ p)
{
    const int g = blockIdx.x * 256 + threadIdx.x;
    const int c = g & (C_ - 1);
    const int j = (g >> 10) & (NC - 1);
    const int b = g >> 14;
    const float w = -__expf(tdec[c]);
    const float u = tfirst[c];

    float aa = 0.f, bb = 0.f, pp = -1e38f;
    for (int i = 0; i < j; ++i) {
        const float4 s = st[((size_t)b * NC + i) * C_ + c];
        const float pdec = pp + w * (float)LCH;
        const float q  = fmaxf(pdec, s.z);
        const float eA = __expf(pdec - q);
        const float eB = __expf(s.z - q);
        aa = eA * aa + eB * s.x;
        bb = eA * bb + eB * s.y;
        pp = q;
    }

    const size_t base = ((size_t)(b * T_ + j * LCH)) * C_ + c;
    #pragma unroll 4
    for (int t = 0; t < LCH; ++t) {
        const size_t idx = base + (size_t)t * C_;
        const float kt = bf2f(kb[idx]);
        const float vt = bf2f(vb[idx]);
        const float ww = u + kt;
        const float qq = fmaxf(pp, ww);
        const float e1 = __expf(pp - qq);
        const float e2 = __expf(ww - qq);
        const float y  = (e1 * aa + e2 * vt) / (e1 * bb + e2);
        p[idx] = f2bf(bf2f(sr[idx]) * y);
        const float ww2 = pp + w;
        const float qq2 = fmaxf(ww2, kt);
        const float e1b = __expf(ww2 - qq2);
        const float e2b = __expf(kt - qq2);
        aa = e1b * aa + e2b * vt;
        bb = e1b * bb + e2b;
        pp = qq2;
    }
}

// ---------------------------------------------------------------------------
// 4-phase/K-tile GEMM core (T2+T3+T4+T5): BM=BN=256, BK=64, 8 waves (2Mx4N),
// per-wave C = 128x64 (acc[8][4] 16x16 frags). LDS = 2 slots per matrix
// (slot = 256x64 bf16 = 32 KiB; A 64 KiB + B 64 KiB = 128 KiB). 1 block/CU.
//
// LDS geometry = round-0's PROVEN ZERO-CONFLICT pattern: rows of 64 ushorts
// (128 B), 16B block q of row r stored at physical q ^ (r & 7). Applied by
// pre-swizzling the global SOURCE (LDS dest stays linear for global_load_lds)
// and XOR-ing the read block index (rule #21, both-sides-or-neither).
//
// Staging units: 64 rows x 128 B = 8 KiB = 1 global_load_lds per thread.
// A units {0,2} = rows read by acc-rows 0-3 (both wm bands); units {1,3} =
// acc-rows 4-7. B unit wn = wave's 64 N-rows (read at F0 only, reg-held).
//
// Per K-tile t (slot t&1), 4 phases; stage tile t+1 into slot (t&1)^1:
//   F0: read all 8 B-frags + A-frags 0,1 | stage A(t+1) units {0,2} | 16 MFMA
//   F1: read A-frags 2,3                 | stage B(t+1) units {0..3}| 16 MFMA
//       -> vmcnt(6): proves A(t) h1 (staged F2 of t-1); leaves this tile's
//          6 newest stage-loads in flight (T4: never drain).
//   F2: read A-frags 4,5                 | stage A(t+1) units {1,3} | 16 MFMA
//   F3: read A-frags 6,7                 | no stage                 | 16 MFMA
//       -> vmcnt(2): proves A(t+1) h0 + B(t+1) (staged F0,F1); leaves F2's 2.
// WAR is structural: stages during tile t only touch slot (t&1)^1, whose last
// reads ended a full tile (>=2 barriers + lgkmcnt(0)) earlier.
// Each phase: [ds_read; stage; barrier; lgkmcnt(0); setprio(1); MFMA;
// setprio(0); (counted vmcnt); barrier].
// ---------------------------------------------------------------------------
static __device__ __forceinline__ void gemm_core256(
    const unsigned short* __restrict__ A, int lda,
    const unsigned short* __restrict__ Bw, int ldb,
    int K, int m0, int n0,
    unsigned short* As, unsigned short* Bs, f32x4 acc[8][4])
{
    const int tid  = threadIdx.x;
    const int l    = tid & 63;
    const int l16  = l & 15, quad = l >> 4;
    const int w    = tid >> 6;
    const int wm   = w >> 2, wn = w & 3;        // 2 x 4 wave grid

    // ---- staging source addressing (pre-swizzled global, linear LDS dest)
    // dest row within 64-row unit = tid>>3 (8 threads x 16B = one 128B row);
    // dest block = tid&7; logical source block = dest ^ (row & 7).
    const int sr_ = tid >> 3;                    // 0..63
    const int sb_ = (tid & 7) ^ (sr_ & 7);       // swizzled 16B source block
    const unsigned short* gA = A  + (size_t)(m0 + sr_) * lda + sb_ * 8;
    const unsigned short* gB = Bw + (size_t)(n0 + sr_) * ldb + sb_ * 8;

    auto stA = [&](int tt, int ss, int u) {
        GLDS16(gA + (size_t)u * 64 * lda + tt * 64, As + ss * 16384 + u * 4096 + w * 512);
    };
    auto stB = [&](int tt, int ss, int u) {
        GLDS16(gB + (size_t)u * 64 * ldb + tt * 64, Bs + ss * 16384 + u * 4096 + w * 512);
    };

    // ---- fragment read addressing: row = band + frag*16 + l16 (row&7 = l16&7);
    // logical block = s*4 + quad (K-step s), physical = logical ^ (l16&7).
    const int swz = l16 & 7;
    const unsigned short* aR = As + (wm * 128 + l16) * 64;
    const unsigned short* bR = Bs + (wn * 64  + l16) * 64;
    const int o0 = ((0 + quad) ^ swz) * 8;       // K-step 0
    const int o1 = ((4 + quad) ^ swz) * 8;       // K-step 1

    // ---- prologue: stage tile 0 fully, one-time drain
    stA(0, 0, 0); stA(0, 0, 2);
    stB(0, 0, 0); stB(0, 0, 1); stB(0, 0, 2); stB(0, 0, 3);
    stA(0, 0, 1); stA(0, 0, 3);
    asm volatile("s_waitcnt vmcnt(0)" ::: "memory");
    SB0();
    __builtin_amdgcn_s_barrier();
    SB0();

    const int NT = K >> 6;
    for (int t = 0; t < NT; ++t) {
        const int rs = t & 1, ns = rs ^ 1;
        const unsigned short* ab = aR + rs * 16384;
        const unsigned short* bb = bR + rs * 16384;
        const bool pf = (t + 1 < NT);
        bf16x8 b0[4], b1[4];

        // ===== F0: all B frags + A frags 0,1; stage A(t+1) units {0,2} =====
        {
            bf16x8 a0[2], a1[2];
            #pragma unroll
            for (int j = 0; j < 4; ++j) {
                b0[j] = *(const bf16x8*)(bb + j * 1024 + o0);
                b1[j] = *(const bf16x8*)(bb + j * 1024 + o1);
            }
            #pragma unroll
            for (int i = 0; i < 2; ++i) {
                a0[i] = *(const bf16x8*)(ab + i * 1024 + o0);
                a1[i] = *(const bf16x8*)(ab + i * 1024 + o1);
            }
            if (pf) { stA(t + 1, ns, 0); stA(t + 1, ns, 2); }
            SB0();
            __builtin_amdgcn_s_barrier();
            asm volatile("s_waitcnt lgkmcnt(0)" ::: "memory");
            SB0();
            __builtin_amdgcn_s_setprio(1);
            #pragma unroll
            for (int i = 0; i < 2; ++i)
                #pragma unroll
                for (int j = 0; j < 4; ++j) {
                    acc[i][j] = MFMA_BF16(a0[i], b0[j], acc[i][j]);
                    acc[i][j] = MFMA_BF16(a1[i], b1[j], acc[i][j]);
                }
            __builtin_amdgcn_s_setprio(0);
            SB0();
            __builtin_amdgcn_s_barrier();
            SB0();
        }

        // ===== F1: A frags 2,3; stage B(t+1) all; vmcnt(6) proves A(t) h1 =====
        {
            bf16x8 a0[2], a1[2];
            #pragma unroll
            for (int i = 0; i < 2; ++i) {
                a0[i] = *(const bf16x8*)(ab + (2 + i) * 1024 + o0);
                a1[i] = *(const bf16x8*)(ab + (2 + i) * 1024 + o1);
            }
            if (pf) { stB(t + 1, ns, 0); stB(t + 1, ns, 1); stB(t + 1, ns, 2); stB(t + 1, ns, 3); }
            SB0();
            __builtin_amdgcn_s_barrier();
            asm volatile("s_waitcnt lgkmcnt(0)" ::: "memory");
            SB0();
            __builtin_amdgcn_s_setprio(1);
            #pragma unroll
            for (int i = 0; i < 2; ++i)
                #pragma unroll
                for (int j = 0; j < 4; ++j) {
                    acc[2 + i][j] = MFMA_BF16(a0[i], b0[j], acc[2 + i][j]);
                    acc[2 + i][j] = MFMA_BF16(a1[i], b1[j], acc[2 + i][j]);
                }
            __builtin_amdgcn_s_setprio(0);
            asm volatile("s_waitcnt vmcnt(6)" ::: "memory");
            SB0();
            __builtin_amdgcn_s_barrier();
            SB0();
        }

        // ===== F2: A frags 4,5; stage A(t+1) units {1,3} =====
        {
            bf16x8 a0[2], a1[2];
            #pragma unroll
            for (int i = 0; i < 2; ++i) {
                a0[i] = *(const bf16x8*)(ab + (4 + i) * 1024 + o0);
                a1[i] = *(const bf16x8*)(ab + (4 + i) * 1024 + o1);
            }
            if (pf) { stA(t + 1, ns, 1); stA(t + 1, ns, 3); }
            SB0();
            __builtin_amdgcn_s_barrier();
            asm volatile("s_waitcnt lgkmcnt(0)" ::: "memory");
            SB0();
            __builtin_amdgcn_s_setprio(1);
            #pragma unroll
            for (int i = 0; i < 2; ++i)
                #pragma unroll
                for (int j = 0; j < 4; ++j) {
                    acc[4 + i][j] = MFMA_BF16(a0[i], b0[j], acc[4 + i][j]);
                    acc[4 + i][j] = MFMA_BF16(a1[i], b1[j], acc[4 + i][j]);
                }
            __builtin_amdgcn_s_setprio(0);
            SB0();
            __builtin_amdgcn_s_barrier();
            SB0();
        }

        // ===== F3: A frags 6,7; vmcnt(2) proves A(t+1) h0 + B(t+1) =====
        {
            bf16x8 a0[2], a1[2];
            #pragma unroll
            for (int i = 0; i < 2; ++i) {
                a0[i] = *(const bf16x8*)(ab + (6 + i) * 1024 + o0);
                a1[i] = *(const bf16x8*)(ab + (6 + i) * 1024 + o1);
            }
            SB0();
            __builtin_amdgcn_s_barrier();
            asm volatile("s_waitcnt lgkmcnt(0)" ::: "memory");
            SB0();
            __builtin_amdgcn_s_setprio(1);
            #pragma unroll
            for (int i = 0; i < 2; ++i)
                #pragma unroll
                for (int j = 0; j < 4; ++j) {
                    acc[6 + i][j] = MFMA_BF16(a0[i], b0[j], acc[6 + i][j]);
                    acc[6 + i][j] = MFMA_BF16(a1[i], b1[j], acc[6 + i][j]);
                }
            __builtin_amdgcn_s_setprio(0);
            asm volatile("s_waitcnt vmcnt(2)" ::: "memory");
            SB0();
            __builtin_amdgcn_s_barrier();
            SB0();
        }
    }
}

// Generic GEMM. EPI: 1 = sigmoid->bf16; 2 = resid + acc -> fp32;
//                3 = relu(acc)^2 -> bf16; 4 = outF += bf16(mul)*acc
template<int EPI>
__global__ __launch_bounds__(512, 1) void k_gemm(
    const unsigned short* __restrict__ A, int lda,
    const unsigned short* __restrict__ Bw, int ldb,
    int K, int N,
    float* __restrict__ outF, unsigned short* __restrict__ outH,
    const float* __restrict__ resid, const unsigned short* __restrict__ mul)
{
    __shared__ unsigned short As[2 * 16384];   // 64 KiB
    __shared__ unsigned short Bs[2 * 16384];   // 64 KiB
    f32x4 acc[8][4];
    const f32x4 zero = {0.f, 0.f, 0.f, 0.f};
    #pragma unroll
    for (int i = 0; i < 8; ++i)
        #pragma unroll
        for (int j = 0; j < 4; ++j) acc[i][j] = zero;

    const int m0 = blockIdx.x * 256, n0 = blockIdx.y * 256;
    gemm_core256(A, lda, Bw, ldb, K, m0, n0, As, Bs, acc);

    const int lane = threadIdx.x & 63, wave = threadIdx.x >> 6;
    const int quad = lane >> 4, l16 = lane & 15;
    const int wm = (wave >> 2) * 128, wn = (wave & 3) * 64;
    #pragma unroll
    for (int i = 0; i < 8; ++i) {
        const int rowb = m0 + wm + i * 16 + quad * 4;
        #pragma unroll
        for (int j = 0; j < 4; ++j) {
            const int col = n0 + wn + j * 16 + l16;
            #pragma unroll
            for (int r = 0; r < 4; ++r) {
                const size_t idx = (size_t)(rowb + r) * N + col;
                const float v = acc[i][j][r];
                if (EPI == 1)      outH[idx] = f2bf(1.f / (1.f + __expf(-v)));
                else if (EPI == 2) outF[idx] = resid[idx] + v;
                else if (EPI == 3) { const float z = v > 0.f ? v : 0.f; outH[idx] = f2bf(z * z); }
                else               outF[idx] = outF[idx] + bf2f(mul[idx]) * v;
            }
        }
    }
}

// Fused k/v/r projection: one dispatch vs packed [Wk;Wv;Wr] (N=3072).
// n-segment (n0>>10, uniform per block) selects BOTH the A input (xk/xv/xr)
// and the output (k->ok, v->ov, sigmoid(r)->orr). 256-tiles divide 1024.
__global__ __launch_bounds__(512, 1) void k_gemm_kvr(
    const unsigned short* __restrict__ xk, const unsigned short* __restrict__ xv,
    const unsigned short* __restrict__ xr,
    const unsigned short* __restrict__ W3,
    unsigned short* __restrict__ ok, unsigned short* __restrict__ ov,
    unsigned short* __restrict__ orr)
{
    __shared__ unsigned short As[2 * 16384];
    __shared__ unsigned short Bs[2 * 16384];
    f32x4 acc[8][4];
    const f32x4 zero = {0.f, 0.f, 0.f, 0.f};
    #pragma unroll
    for (int i = 0; i < 8; ++i)
        #pragma unroll
        for (int j = 0; j < 4; ++j) acc[i][j] = zero;

    const int m0 = blockIdx.x * 256, n0 = blockIdx.y * 256;
    const int seg = n0 >> 10;                       // 0=k 1=v 2=r
    const unsigned short* A = (seg == 0) ? xk : (seg == 1) ? xv : xr;
    unsigned short* outH    = (seg == 0) ? ok : (seg == 1) ? ov : orr;

    gemm_core256(A, C_, W3, C_, C_, m0, n0, As, Bs, acc);

    const int nl0 = n0 & (C_ - 1);
    const int lane = threadIdx.x & 63, wave = threadIdx.x >> 6;
    const int quad = lane >> 4, l16 = lane & 15;
    const int wm = (wave >> 2) * 128, wn = (wave & 3) * 64;
    #pragma unroll
    for (int i = 0; i < 8; ++i) {
        const int rowb = m0 + wm + i * 16 + quad * 4;
        #pragma unroll
        for (int j = 0; j < 4; ++j) {
            const int col = nl0 + wn + j * 16 + l16;
            #pragma unroll
            for (int r = 0; r < 4; ++r) {
                const size_t idx = (size_t)(rowb + r) * C_ + col;
                float v = acc[i][j][r];
                if (seg == 2) v = 1.f / (1.f + __expf(-v));
                outH[idx] = f2bf(v);
            }
        }
    }
}

// ---------------------------------------------------------------------------
// Workspace layout (peak 154 MB):
//   [0,32)MB    xk   -> WKV states (2MB) -> xk2
//   [32,64)     xv   -> p    -> tmp (FFN chunk)
//   [64,96)     xr   -> xr2
//   [96,128)    sr   -> s2
//   [128,154)   bf16 weights ([Wk;Wv;Wr] contiguous for fused GEMM)
// k,v (bf16, 32MB each) live in d_out until step 5 overwrites it.
// ---------------------------------------------------------------------------
extern "C" void kernel_launch(void* const* d_in, const int* in_sizes, int n_in,
                              void* d_out, int out_size, void* d_ws, size_t ws_size,
                              hipStream_t stream)
{
    const float* x      = (const float*)d_in[0];
    const float* ln1w   = (const float*)d_in[1];
    const float* ln1b   = (const float*)d_in[2];
    const float* ln2w   = (const float*)d_in[3];
    const float* ln2b   = (const float*)d_in[4];
    const float* atk    = (const float*)d_in[5];
    const float* atv    = (const float*)d_in[6];
    const float* atr    = (const float*)d_in[7];
    const float* tdec   = (const float*)d_in[8];
    const float* tfirst = (const float*)d_in[9];
    const float* Wk     = (const float*)d_in[10];
    const float* Wv     = (const float*)d_in[11];
    const float* Wr     = (const float*)d_in[12];
    const float* Wo     = (const float*)d_in[13];
    const float* ftk    = (const float*)d_in[14];
    const float* ftr    = (const float*)d_in[15];
    const float* Wkey   = (const float*)d_in[16];
    const float* Wrec   = (const float*)d_in[17];
    const float* Wval   = (const float*)d_in[18];
    float* out = (float*)d_out;

    char* ws = (char*)d_ws;
    const size_t MB = 1ull << 20;
    unsigned short* xk  = (unsigned short*)(ws + 0 * MB);
    unsigned short* xv  = (unsigned short*)(ws + 32 * MB);
    unsigned short* xr  = (unsigned short*)(ws + 64 * MB);
    unsigned short* sr  = (unsigned short*)(ws + 96 * MB);
    unsigned short* wb  = (unsigned short*)(ws + 128 * MB);
    float4* states      = (float4*)(ws + 0 * MB);   // 2MB, xk dead after kvr GEMM
    unsigned short* p   = xv;   // p overwrites xv (dead after kvr GEMM)
    unsigned short* xk2 = xk;
    unsigned short* xr2 = xr;
    unsigned short* s2  = sr;
    unsigned short* tmp = xv;   // FFN chunk buffer (p dead after Wo-GEMM)
    unsigned short* kb  = (unsigned short*)d_out;             // 32MB
    unsigned short* vb  = (unsigned short*)d_out + (32*MB/2); // 32MB

    unsigned short* W3_b   = wb;                   // [Wk;Wv;Wr] 3072x1024
    unsigned short* Wo_b   = wb + 3 * (1u << 20);
    unsigned short* Wrec_b = wb + 4 * (1u << 20);
    unsigned short* Wkey_b = wb + 5 * (1u << 20);
    unsigned short* Wval_b = wb + 9 * (1u << 20);

    // 1) weights -> bf16
    WSrc wsrc; wsrc.p[0]=Wk; wsrc.p[1]=Wv; wsrc.p[2]=Wr; wsrc.p[3]=Wo;
    wsrc.p[4]=Wrec; wsrc.p[5]=Wkey; wsrc.p[6]=Wval;
    k_convert<<<dim3(13312), dim3(256), 0, stream>>>(wsrc, wb);

    // 2) LN1 + time-shift mix -> xk, xv, xr (bf16)
    k_ln_mix<1><<<dim3(M_), dim3(256), 0, stream>>>(x, ln1w, ln1b, atk, atv, atr, xk, xv, xr);

    // 3) fused k/v/r projections (N=3072): k->kb, v->vb, sigmoid(r)->sr
    k_gemm_kvr<<<dim3(64, 12), dim3(512), 0, stream>>>(xk, xv, xr, W3_b, kb, vb, sr);

    // 4) WKV: chunk-parallel scan
    k_wkv_local<<<dim3(512), dim3(256), 0, stream>>>(kb, vb, tdec, states);
    k_wkv_scan<<<dim3(512), dim3(256), 0, stream>>>(kb, vb, sr, tdec, tfirst, states, p);

    // 5) x1 = x + p @ Wo^T -> d_out (fp32)
    k_gemm<2><<<dim3(64, 4), dim3(512), 0, stream>>>(p, 1024, Wo_b, 1024, 1024, 1024, out, (unsigned short*)nullptr, x, (const unsigned short*)nullptr);

    // 6) LN2 + time-shift mix -> xk2, xr2 (bf16)
    k_ln_mix<0><<<dim3(M_), dim3(256), 0, stream>>>(out, ln2w, ln2b, ftk, (const float*)nullptr, ftr, xk2, (unsigned short*)nullptr, xr2);

    // 7) s2 = sigmoid(xr2 @ Wrec^T) (bf16)
    k_gemm<1><<<dim3(64, 4), dim3(512), 0, stream>>>(xr2, 1024, Wrec_b, 1024, 1024, 1024, (float*)nullptr, s2, (const float*)nullptr, (const unsigned short*)nullptr);

    // 8) FFN chunked over F (4 x 1024): out += s2 * (relu(xk2@Wkey_f^T)^2 @ Wval_f^T)
    for (int f = 0; f < 4; ++f) {
        const unsigned short* WkeyF = Wkey_b + (size_t)f * 1024 * 1024;
        const unsigned short* WvalF = Wval_b + (size_t)f * 1024;
        k_gemm<3><<<dim3(64, 4), dim3(512), 0, stream>>>(xk2, 1024, WkeyF, 1024, 1024, 1024, (float*)nullptr, tmp, (const float*)nullptr, (const unsigned short*)nullptr);
        k_gemm<4><<<dim3(64, 4), dim3(512), 0, stream>>>(tmp, 1024, WvalF, 4096, 1024, 1024, out, (unsigned short*)nullptr, (const float*)nullptr, s2);
    }
}